// Round 14
// baseline (2087.825 us; speedup 1.0000x reference)
//
#include <hip/hip_runtime.h>

#define DEV __device__ __forceinline__

typedef short s4v __attribute__((ext_vector_type(4)));
typedef short s8v __attribute__((ext_vector_type(8)));
typedef float f4v __attribute__((ext_vector_type(4)));
typedef unsigned int u32x2 __attribute__((ext_vector_type(2)));

DEV short f2bf(float f) {
  unsigned u = __float_as_uint(f);
  u += 0x7FFFu + ((u >> 16) & 1u);
  return (short)(u >> 16);
}
DEV short f2bf_fast(float f) {           // round-half-up (positive finite)
  return (short)((__float_as_uint(f) + 0x8000u) >> 16);
}
DEV float bf2f(short s) { return __uint_as_float(((unsigned)(unsigned short)s) << 16); }

DEV void gld_lds16(const short* g, short* l) {
  __builtin_amdgcn_global_load_lds(
      (const __attribute__((address_space(1))) void*)g,
      (__attribute__((address_space(3))) void*)l, 16, 0, 0);
}

// LDS transpose read (4x16 bf16 subtile, lane gets column lane&15)
DEV u32x2 trr(unsigned lds_byte) {
  u32x2 r;
  asm volatile("ds_read_b64_tr_b16 %0, %1" : "=&v"(r) : "v"(lds_byte));
  return r;
}

// XCD-bijective swizzle (m204)
DEV int xcd_swz(int id, int nwg) {
  int q8 = nwg >> 3, r8 = nwg & 7, xcd = id & 7, off = id >> 3;
  return (xcd < r8) ? (xcd * (q8 + 1) + off) : (r8 * (q8 + 1) + (xcd - r8) * q8 + off);
}

// ================= 64xBN tile bf16 BT GEMM, dbuf + chunk-swizzle =================
// BN=128: waves 1x4. BN=64: waves 2x2.
// flags: 1=+bias[col] (z==0 only), 2=exact GELU, 4=accumulate into fp32 C, 8=bf16 out
// K-split: blockIdx.z picks chunk of K/ksplit; C base += z * zCoff.
template<int BN>
__global__ __launch_bounds__(256) void gemm_t(
    const short* __restrict__ A, const short* __restrict__ B, void* __restrict__ Cv,
    const float* __restrict__ bias,
    int M, int N, int K, int lda, int ldb, int ldc, int flags, int ksplit, long zCoff)
{
  constexpr int BPASS = BN / 32;
  constexpr int MI = (BN == 128) ? 4 : 2;
  __shared__ __align__(16) short As[2][64 * 64];
  __shared__ __align__(16) short Bs[2][BN * 64];
  int nwg = gridDim.x * gridDim.y;
  int idl = blockIdx.y * gridDim.x + blockIdx.x;
  int swz = xcd_swz(idl, nwg);
  int bx = swz % gridDim.x, by = swz / gridDim.x;
  int m0 = by * 64, n0 = bx * BN;
  int tid = threadIdx.x, lane = tid & 63, w = tid >> 6;
  int lr = lane & 15, kg = lane >> 4;
  int wrb = (BN == 128) ? 0 : (w >> 1) * 32;
  int wcb = (BN == 128) ? w * 32 : (w & 1) * 32;
  f4v acc[MI][2] = {};
  int KH = K / ksplit;
  int kbase = blockIdx.z * KH;
  int NT = KH >> 6;

#define STAGE(bufi, k0)                                                   \
  {                                                                       \
    _Pragma("unroll")                                                     \
    for (int p = 0; p < 2; ++p) {                                         \
      int ch = p * 256 + w * 64 + lane;                                   \
      int row = ch >> 3, c = (ch & 7) ^ (row & 7);                        \
      gld_lds16(A + (long)(m0 + row) * lda + (k0) + c * 8,                \
                &As[bufi][(p * 256 + w * 64) * 8]);                       \
    }                                                                     \
    _Pragma("unroll")                                                     \
    for (int p = 0; p < BPASS; ++p) {                                     \
      int ch = p * 256 + w * 64 + lane;                                   \
      int row = ch >> 3, c = (ch & 7) ^ (row & 7);                        \
      gld_lds16(B + (long)(n0 + row) * ldb + (k0) + c * 8,                \
                &Bs[bufi][(p * 256 + w * 64) * 8]);                       \
    }                                                                     \
  }

  STAGE(0, kbase)
  for (int t = 0; t < NT; ++t) {
    int buf = t & 1;
    if (t + 1 < NT) {
      STAGE(buf ^ 1, kbase + (t + 1) * 64)
      if constexpr (BN == 128)
        asm volatile("s_waitcnt vmcnt(6)" ::: "memory");
      else
        asm volatile("s_waitcnt vmcnt(4)" ::: "memory");
    } else {
      asm volatile("s_waitcnt vmcnt(0)" ::: "memory");
    }
    __builtin_amdgcn_s_barrier();
    #pragma unroll
    for (int ks = 0; ks < 2; ++ks) {
      s8v av[MI], bv[2];
      #pragma unroll
      for (int mi = 0; mi < MI; ++mi) {
        int row = wrb + mi * 16 + lr;
        int sl = (ks * 4 + kg) ^ (row & 7);
        av[mi] = *(const s8v*)&As[buf][row * 64 + sl * 8];
      }
      #pragma unroll
      for (int ni = 0; ni < 2; ++ni) {
        int row = wcb + ni * 16 + lr;
        int sl = (ks * 4 + kg) ^ (row & 7);
        bv[ni] = *(const s8v*)&Bs[buf][row * 64 + sl * 8];
      }
      #pragma unroll
      for (int mi = 0; mi < MI; ++mi)
        #pragma unroll
        for (int ni = 0; ni < 2; ++ni)
          acc[mi][ni] = __builtin_amdgcn_mfma_f32_16x16x32_bf16(av[mi], bv[ni], acc[mi][ni], 0, 0, 0);
    }
    asm volatile("s_waitcnt lgkmcnt(0)" ::: "memory");
    __builtin_amdgcn_s_barrier();
  }
#undef STAGE

  float* Cf = (float*)Cv + blockIdx.z * zCoff;
  short* Cb = (short*)Cv + blockIdx.z * zCoff;
  bool dob = (flags & 1) && blockIdx.z == 0;
  #pragma unroll
  for (int mi = 0; mi < MI; ++mi)
    #pragma unroll
    for (int ni = 0; ni < 2; ++ni) {
      int col = n0 + wcb + ni * 16 + lr;
      float bvv = dob ? bias[col] : 0.f;
      #pragma unroll
      for (int j = 0; j < 4; ++j) {
        int row = m0 + wrb + mi * 16 + kg * 4 + j;
        if (row >= M) continue;
        float v = acc[mi][ni][j] + bvv;
        if (flags & 2) v = 0.5f * v * (1.f + erff(v * 0.70710678118f));
        long ci = (long)row * ldc + col;
        if (flags & 8) Cb[ci] = f2bf(v);
        else { if (flags & 4) v += Cf[ci]; Cf[ci] = v; }
      }
    }
}

// ---------------- fused flash attention: in-block 2-way KV split ----------------
// grid 544 = 32 z * 17 qtiles; block 512 = 2 groups * 4 waves.
__global__ __launch_bounds__(512) void flash_k(
    const short* __restrict__ qkv, short* __restrict__ O)
{
  int swz = xcd_swz(blockIdx.x, 544);
  int z = swz / 17, qt = swz - z * 17;
  int zb = z >> 3, zh = z & 7;
  const short* base = qkv + (long)zb * 1025 * 1536 + zh * 192;
  const short* Qg = base;
  const short* Kg = base + 64;
  const short* Vg = base + 128;
  int q0 = qt * 64;
  int tid = threadIdx.x, lane = tid & 63, w = tid >> 6;
  int g = w >> 2, wl = w & 3;
  int lr = lane & 15, kg = lane >> 4;
  int kt0 = g * 8;

  __shared__ __align__(16) short Ks[2][2][64 * 64];
  __shared__ __align__(16) short Vs[2][2][64 * 64];

  s8v aq[2];
  {
    long qrow = q0 + wl * 16 + lr;
    aq[0] = *(const s8v*)(Qg + qrow * 1536 + kg * 8);
    aq[1] = *(const s8v*)(Qg + qrow * 1536 + 32 + kg * 8);
  }

  unsigned vsbase = (unsigned)(unsigned long long)
      (__attribute__((address_space(3))) void*)&Vs[0][0][0];
  unsigned vtr = (unsigned)(lr * 8 + kg * 1024);

#define STAGE_K(bufi, kv0)                                                 \
  {                                                                        \
    int s0 = wl * 128;                                                     \
    _Pragma("unroll")                                                      \
    for (int i = 0; i < 2; ++i) {                                          \
      int s = s0 + i * 64 + lane;                                          \
      int row = s >> 3, c = (s & 7) ^ (row & 7);                           \
      gld_lds16(Kg + (long)((kv0) + row) * 1536 + c * 8,                   \
                &Ks[g][bufi][(s0 + i * 64) * 8]);                          \
    }                                                                      \
  }
#define STAGE_V(bufi, kv0)                                                 \
  {                                                                        \
    int s0 = wl * 128;                                                     \
    _Pragma("unroll")                                                      \
    for (int i = 0; i < 2; ++i) {                                          \
      int ch = s0 + i * 64 + lane;                                         \
      int st = ch >> 3, r = (ch & 7) >> 1, hh = ch & 1;                    \
      int key = (kv0) + (st >> 2) * 4 + r;                                 \
      int d = (st & 3) * 16 + hh * 8;                                      \
      gld_lds16(Vg + (long)key * 1536 + d,                                 \
                &Vs[g][bufi][(s0 + i * 64) * 8]);                          \
    }                                                                      \
  }

  f4v acc[4] = {};
  float m_run = -3.0e38f, l_run = 0.f;
  const float C2 = 0.18033688011112042f;
  const float THR = 44.36f;

  STAGE_K(0, kt0 * 64)
  STAGE_V(0, kt0 * 64)
  asm volatile("s_waitcnt vmcnt(0)" ::: "memory");
  __builtin_amdgcn_s_barrier();

  for (int kt = kt0; kt < kt0 + 8; ++kt) {
    int cur = (kt - kt0) & 1;
    if (kt + 1 < kt0 + 8) {
      STAGE_K(cur ^ 1, (kt + 1) * 64)
      STAGE_V(cur ^ 1, (kt + 1) * 64)
    }

    f4v sa[4] = {};
    __builtin_amdgcn_s_setprio(1);
    #pragma unroll
    for (int ni = 0; ni < 4; ++ni) {
      int row = ni * 16 + lr;
      #pragma unroll
      for (int ks = 0; ks < 2; ++ks) {
        int c = (ks * 4 + kg) ^ (row & 7);
        s8v kf = *(const s8v*)&Ks[g][cur][row * 64 + c * 8];
        sa[ni] = __builtin_amdgcn_mfma_f32_16x16x32_bf16(kf, aq[ks], sa[ni], 0, 0, 0);
      }
    }
    __builtin_amdgcn_s_setprio(0);

    float tm = -3.0e38f;
    #pragma unroll
    for (int ni = 0; ni < 4; ++ni)
      #pragma unroll
      for (int jj = 0; jj < 4; ++jj) tm = fmaxf(tm, sa[ni][jj]);
    tm = fmaxf(tm, __shfl_xor(tm, 16));
    tm = fmaxf(tm, __shfl_xor(tm, 32));
    bool need = !__all(tm <= m_run + THR);
    float scale = 1.f;
    if (need) {
      float m_new = fmaxf(m_run, tm);
      scale = exp2f((m_run - m_new) * C2);
      m_run = m_new;
    }
    float mC = m_run * C2;
    float pv[4][4];
    float ts = 0.f;
    #pragma unroll
    for (int ni = 0; ni < 4; ++ni)
      #pragma unroll
      for (int jj = 0; jj < 4; ++jj) {
        float p = exp2f(fmaf(sa[ni][jj], C2, -mC));
        pv[ni][jj] = p;
        ts += p;
      }
    ts += __shfl_xor(ts, 16);
    ts += __shfl_xor(ts, 32);
    l_run = l_run * scale + ts;
    if (need) {
      float scq[4];
      #pragma unroll
      for (int jj = 0; jj < 4; ++jj)
        scq[jj] = __shfl(scale, kg * 4 + jj + 16 * kg);
      #pragma unroll
      for (int ni = 0; ni < 4; ++ni)
        #pragma unroll
        for (int jj = 0; jj < 4; ++jj) acc[ni][jj] *= scq[jj];
    }

    unsigned pr[4][2];
    #pragma unroll
    for (int ni = 0; ni < 4; ++ni)
      #pragma unroll
      for (int hh = 0; hh < 2; ++hh) {
        unsigned lo = (unsigned)(unsigned short)f2bf_fast(pv[ni][2 * hh]);
        unsigned hi = (unsigned)(unsigned short)f2bf_fast(pv[ni][2 * hh + 1]);
        pr[ni][hh] = lo | (hi << 16);
      }
    union PU { s8v v; unsigned u[4]; };
    PU apu[2];
    #pragma unroll
    for (int ks = 0; ks < 2; ++ks)
      #pragma unroll
      for (int t = 0; t < 4; ++t) {
        unsigned src = (kg & 2) ? pr[2 * ks + 1][t & 1] : pr[2 * ks][t & 1];
        apu[ks].u[t] = __shfl(src, lr + 16 * (2 * (kg & 1) + (t >> 1)));
      }

    u32x2 tr[4][2][2];
    unsigned vb = vsbase + (unsigned)(g * 2 + cur) * 8192u + vtr;
    #pragma unroll
    for (int ni = 0; ni < 4; ++ni)
      #pragma unroll
      for (int ks = 0; ks < 2; ++ks) {
        tr[ni][ks][0] = trr(vb + ni * 128 + ks * 4096);
        tr[ni][ks][1] = trr(vb + ni * 128 + ks * 4096 + 512);
      }
    asm volatile("s_waitcnt lgkmcnt(0)" ::: "memory");
    __builtin_amdgcn_sched_barrier(0);

    __builtin_amdgcn_s_setprio(1);
    #pragma unroll
    for (int ni = 0; ni < 4; ++ni) {
      #pragma unroll
      for (int ks = 0; ks < 2; ++ks) {
        union { s8v v; u32x2 u2[2]; } bb;
        bb.u2[0] = tr[ni][ks][0];
        bb.u2[1] = tr[ni][ks][1];
        acc[ni] = __builtin_amdgcn_mfma_f32_16x16x32_bf16(apu[ks].v, bb.v, acc[ni], 0, 0, 0);
      }
    }
    __builtin_amdgcn_s_setprio(0);
    asm volatile("s_waitcnt lgkmcnt(0)" ::: "memory");
    asm volatile("s_waitcnt vmcnt(0)" ::: "memory");
    __builtin_amdgcn_s_barrier();
  }
#undef STAGE_K
#undef STAGE_V

  if (g) {
    s8v k0 = *(const s8v*)(Kg + 1024L * 1536 + kg * 8);
    s8v k1 = *(const s8v*)(Kg + 1024L * 1536 + 32 + kg * 8);
    float s = 0.f;
    #pragma unroll
    for (int j = 0; j < 8; ++j)
      s += bf2f(aq[0][j]) * bf2f(k0[j]) + bf2f(aq[1][j]) * bf2f(k1[j]);
    s += __shfl_xor(s, 16);
    s += __shfl_xor(s, 32);
    float m_new = fmaxf(m_run, s);
    float sc = exp2f((m_run - m_new) * C2);
    float p = exp2f((s - m_new) * C2);
    m_run = m_new;
    l_run = l_run * sc + p;
    float vrow[4];
    #pragma unroll
    for (int ni = 0; ni < 4; ++ni)
      vrow[ni] = bf2f(Vg[1024L * 1536 + ni * 16 + lr]);
    float scq[4], pq[4];
    #pragma unroll
    for (int jj = 0; jj < 4; ++jj) {
      scq[jj] = __shfl(sc, kg * 4 + jj + 16 * kg);
      pq[jj]  = __shfl(p,  kg * 4 + jj + 16 * kg);
    }
    #pragma unroll
    for (int ni = 0; ni < 4; ++ni)
      #pragma unroll
      for (int jj = 0; jj < 4; ++jj)
        acc[ni][jj] = acc[ni][jj] * scq[jj] + pq[jj] * vrow[ni];
  }

  // in-block combine (LDS reuse)
  float* AccL = (float*)&Ks[0][0][0];
  float* MLs  = (float*)&Vs[0][0][0];
  if (kg == 0) {
    MLs[(g * 64 + wl * 16 + lr) * 2]     = m_run;
    MLs[(g * 64 + wl * 16 + lr) * 2 + 1] = l_run;
  }
  if (g == 0) {
    #pragma unroll
    for (int ni = 0; ni < 4; ++ni)
      #pragma unroll
      for (int jj = 0; jj < 4; ++jj)
        AccL[(wl * 16 + kg * 4 + jj) * 64 + ni * 16 + lr] = acc[ni][jj];
  }
  asm volatile("s_waitcnt lgkmcnt(0)" ::: "memory");
  __builtin_amdgcn_s_barrier();
  if (g == 1) {
    float m0 = MLs[(wl * 16 + lr) * 2], l0 = MLs[(wl * 16 + lr) * 2 + 1];
    float M = fmaxf(m0, m_run);
    float w0 = exp2f((m0 - M) * C2), w1 = exp2f((m_run - M) * C2);
    float inv = 1.f / (l0 * w0 + l_run * w1);
    float c0 = w0 * inv, c1 = w1 * inv;
    float c0q[4], c1q[4];
    #pragma unroll
    for (int jj = 0; jj < 4; ++jj) {
      c0q[jj] = __shfl(c0, kg * 4 + jj + 16 * kg);
      c1q[jj] = __shfl(c1, kg * 4 + jj + 16 * kg);
    }
    #pragma unroll
    for (int ni = 0; ni < 4; ++ni)
      #pragma unroll
      for (int jj = 0; jj < 4; ++jj) {
        int row = q0 + wl * 16 + kg * 4 + jj;
        if (row < 1025) {
          float a0 = AccL[(wl * 16 + kg * 4 + jj) * 64 + ni * 16 + lr];
          O[((long)(zb * 1025 + row)) * 512 + zh * 64 + ni * 16 + lr] =
              f2bf(a0 * c0q[jj] + acc[ni][jj] * c1q[jj]);
        }
      }
  }
}

// ---------------- fused per-layer weight transpose+convert ----------------
DEV void tconv_body(const float* w, short* wt, int K, int N, int bx, int by, int tid)
{
  __shared__ float tile[32][33];
  int n0 = bx * 32, k0 = by * 32;
  int tx = tid & 31, ty = tid >> 5;
  #pragma unroll
  for (int j = 0; j < 4; ++j)
    tile[ty + j * 8][tx] = w[(long)(k0 + ty + j * 8) * N + n0 + tx];
  __syncthreads();
  #pragma unroll
  for (int j = 0; j < 4; ++j)
    wt[(long)(n0 + ty + j * 8) * K + k0 + tx] = f2bf(tile[tx][ty + j * 8]);
}

__global__ __launch_bounds__(256) void tconv4_k(
    const float* __restrict__ sq, const float* __restrict__ sm,
    const float* __restrict__ sf1, const float* __restrict__ sf2,
    short* __restrict__ dq, short* __restrict__ dm,
    short* __restrict__ df1, short* __restrict__ df2)
{
  int id = blockIdx.x, tid = threadIdx.x;
  if (id < 1152)       tconv_body(sq,  dq,  768, 1536, id % 48,          id / 48,          tid);
  else if (id < 1536)  tconv_body(sm,  dm,  512, 768,  (id - 1152) % 24, (id - 1152) / 24, tid);
  else if (id < 3072)  tconv_body(sf1, df1, 768, 2048, (id - 1536) % 64, (id - 1536) / 64, tid);
  else                 tconv_body(sf2, df2, 2048, 768, (id - 3072) % 24, (id - 3072) / 24, tid);
}

// ---------------- elementwise fp32 -> bf16 ----------------
__global__ __launch_bounds__(256) void cvt_k(const float* __restrict__ in,
    short* __restrict__ out, int n)
{
  int i = blockIdx.x * 256 + threadIdx.x;
  if (i < n) out[i] = f2bf(in[i]);
}

// ---------------- fused partial-add + LayerNorm: one wave per row ----------------
DEV void st4(float* p, f4v v) { *(f4v*)p = v; }
DEV void st4(short* p, f4v v) {
  s4v o = { f2bf(v[0]), f2bf(v[1]), f2bf(v[2]), f2bf(v[3]) };
  *(s4v*)p = o;
}

// y = LN(t + P0 + P1); if xout: t <- t + P0 + P1. P0 may be null (plain LN).
template<typename OT>
__global__ __launch_bounds__(256) void ln_k(const float* __restrict__ x,
    const float* __restrict__ P0, const float* __restrict__ P1,
    const float* __restrict__ g, const float* __restrict__ b,
    OT* __restrict__ y, float* __restrict__ xout, int rows)
{
  int row = blockIdx.x * 4 + (threadIdx.x >> 6);
  if (row >= rows) return;
  int lane = threadIdx.x & 63;
  long rb = (long)row * 768;
  f4v v[3];
  #pragma unroll
  for (int i = 0; i < 3; ++i) v[i] = *(const f4v*)(x + rb + i * 256 + lane * 4);
  if (P0) {
    #pragma unroll
    for (int i = 0; i < 3; ++i) {
      f4v p0 = *(const f4v*)(P0 + rb + i * 256 + lane * 4);
      f4v p1 = *(const f4v*)(P1 + rb + i * 256 + lane * 4);
      #pragma unroll
      for (int j = 0; j < 4; ++j) v[i][j] += p0[j] + p1[j];
    }
    if (xout) {
      #pragma unroll
      for (int i = 0; i < 3; ++i) st4(xout + rb + i * 256 + lane * 4, v[i]);
    }
  }
  float s = 0.f, s2 = 0.f;
  #pragma unroll
  for (int i = 0; i < 3; ++i)
    #pragma unroll
    for (int j = 0; j < 4; ++j) { s += v[i][j]; s2 += v[i][j] * v[i][j]; }
  #pragma unroll
  for (int o = 1; o < 64; o <<= 1) { s += __shfl_xor(s, o); s2 += __shfl_xor(s2, o); }
  float mean = s * (1.f / 768.f);
  float var = s2 * (1.f / 768.f) - mean * mean;
  float r = rsqrtf(var + 1e-5f);
  OT* yr = y + rb;
  #pragma unroll
  for (int i = 0; i < 3; ++i) {
    f4v gg = *(const f4v*)(g + i * 256 + lane * 4);
    f4v bb = *(const f4v*)(b + i * 256 + lane * 4);
    f4v o;
    #pragma unroll
    for (int j = 0; j < 4; ++j) o[j] = (v[i][j] - mean) * r * gg[j] + bb[j];
    st4(yr + i * 256 + lane * 4, o);
  }
}

// ---------------- patch extraction ----------------
__global__ __launch_bounds__(256) void im2col_k(const float* __restrict__ x,
    short* __restrict__ A)
{
  int i = blockIdx.x * 256 + threadIdx.x;
  int k = i & 255, row = i >> 8;
  int px = k & 15, py = k >> 4;
  int gx = row & 31, gy = (row >> 5) & 31, b = row >> 10;
  A[i] = f2bf(x[((long)(b * 512) + gy * 16 + py) * 512 + gx * 16 + px]);
}

// ---------------- t = concat(cls, tok) + pos ----------------
__global__ __launch_bounds__(256) void assemble_k(const short* __restrict__ tok,
    const float* __restrict__ cls, const float* __restrict__ pos, float* __restrict__ t)
{
  int i = blockIdx.x * 256 + threadIdx.x;
  int d = i % 768; int rn = i / 768; int n = rn % 1025; int b = rn / 1025;
  float v = (n == 0) ? cls[d] : bf2f(tok[((long)(b * 1024 + n - 1)) * 768 + d]);
  t[i] = v + pos[n * 768 + d];
}

extern "C" void kernel_launch(void* const* d_in, const int* in_sizes, int n_in,
                              void* d_out, int out_size, void* d_ws, size_t ws_size,
                              hipStream_t stream)
{
  const float* x       = (const float*)d_in[0];
  const float* conv_w  = (const float*)d_in[1];
  const float* conv_b  = (const float*)d_in[2];
  const float* cls     = (const float*)d_in[3];
  const float* pos     = (const float*)d_in[4];
  const float* qkv_w   = (const float*)d_in[5];
  const float* merge_w = (const float*)d_in[6];
  const float* merge_b = (const float*)d_in[7];
  const float* ln1_s   = (const float*)d_in[8];
  const float* ln1_b   = (const float*)d_in[9];
  const float* ln2_s   = (const float*)d_in[10];
  const float* ln2_b   = (const float*)d_in[11];
  const float* ffn_w1  = (const float*)d_in[12];
  const float* ffn_b1  = (const float*)d_in[13];
  const float* ffn_w2  = (const float*)d_in[14];
  const float* ffn_b2  = (const float*)d_in[15];
  const float* lnf_s   = (const float*)d_in[16];
  const float* lnf_b   = (const float*)d_in[17];

  char* wsp = (char*)d_ws;
  size_t o = 0;
  auto take = [&](size_t bytes) { char* r = wsp + o; o = (o + bytes + 255) & ~(size_t)255; return r; };
  short* wq   = (short*)take(1536ul * 768 * 2);
  short* wm   = (short*)take(768ul * 512 * 2);
  short* wf1  = (short*)take(2048ul * 768 * 2);
  short* wf2  = (short*)take(768ul * 2048 * 2);
  short* wcv  = (short*)take(768ul * 256 * 2);
  float* t    = (float*)take(4100ul * 768 * 4);
  float* PA   = (float*)take(2ul * 4100 * 768 * 4);  // split-K partials (2 halves)
  char*  hO   = take(4352ul * 768 * 2);              // h bf16 OR O bf16 (rows padded)
  short* qkv  = (short*)take(4ul * 1025 * 1536 * 2);
  char*  fV   = take(4352ul * 2048 * 2);             // f (padded) OR (im2col + tok)
  take(2ul << 20);                                   // slack for tile over-reads

  short* h   = (short*)hO;
  short* O   = (short*)hO;
  short* f   = (short*)fV;
  short* imc = (short*)fV;
  short* tok = (short*)(fV + 4096ul * 256 * 2);
  const long PZ = 4100L * 768;

  dim3 blk(256), blk512(512);

  // ---- patch embed ----
  cvt_k<<<768, blk, 0, stream>>>(conv_w, wcv, 768 * 256);
  im2col_k<<<4096, blk, 0, stream>>>(x, imc);
  gemm_t<64><<<dim3(12, 64), blk, 0, stream>>>(imc, wcv, tok, conv_b,
      4096, 768, 256, 256, 256, 768, 1 | 8, 1, 0);
  assemble_k<<<12300, blk, 0, stream>>>(tok, cls, pos, t);

  for (int i = 0; i < 12; ++i) {
    tconv4_k<<<4608, blk, 0, stream>>>(
        qkv_w + (long)i * 768 * 1536, merge_w + (long)i * 512 * 768,
        ffn_w1 + (long)i * 768 * 2048, ffn_w2 + (long)i * 2048 * 768,
        wq, wm, wf1, wf2);

    // h = LN1(t [+ prev ffn2 partials])
    ln_k<short><<<1025, blk, 0, stream>>>(t, i ? PA : nullptr, PA + PZ,
        ln1_s + i * 768, ln1_b + i * 768, h, t, 4100);
    // qkv = h @ qkv_w
    gemm_t<64><<<dim3(24, 65), blk, 0, stream>>>(h, wq, qkv, nullptr,
        4100, 1536, 768, 768, 768, 1536, 8, 1, 0);
    // fused attention -> O
    flash_k<<<544, blk512, 0, stream>>>(qkv, O);
    // merge split-K: PA[z] = O @ Wm_half (+bias on z0)
    gemm_t<64><<<dim3(12, 65, 2), blk, 0, stream>>>(O, wm, PA, merge_b + i * 768,
        4100, 768, 512, 512, 512, 768, 1, 2, PZ);
    // h = LN2(t += PA0 + PA1)
    ln_k<short><<<1025, blk, 0, stream>>>(t, PA, PA + PZ,
        ln2_s + i * 768, ln2_b + i * 768, h, t, 4100);
    // f = GELU(h @ ffn_w1 + b1)
    gemm_t<64><<<dim3(32, 65), blk, 0, stream>>>(h, wf1, f, ffn_b1 + i * 2048,
        4100, 2048, 768, 768, 768, 2048, 1 | 2 | 8, 1, 0);
    // ffn2 split-K: PA[z] = f @ W2_half (+bias on z0)
    gemm_t<64><<<dim3(12, 65, 2), blk, 0, stream>>>(f, wf2, PA, ffn_b2 + i * 768,
        4100, 768, 2048, 2048, 2048, 768, 1, 2, PZ);
  }
  // final LN consumes last ffn2 partials (no t writeback needed)
  ln_k<float><<<1025, blk, 0, stream>>>(t, PA, PA + PZ,
      lnf_s, lnf_b, (float*)d_out, nullptr, 4100);
}

// Round 15
// 1996.605 us; speedup vs baseline: 1.0457x; 1.0457x over previous
//
#include <hip/hip_runtime.h>

#define DEV __device__ __forceinline__

typedef short s4v __attribute__((ext_vector_type(4)));
typedef short s8v __attribute__((ext_vector_type(8)));
typedef float f4v __attribute__((ext_vector_type(4)));
typedef unsigned int u32x2 __attribute__((ext_vector_type(2)));

DEV short f2bf(float f) {
  unsigned u = __float_as_uint(f);
  u += 0x7FFFu + ((u >> 16) & 1u);
  return (short)(u >> 16);
}
DEV short f2bf_fast(float f) {           // round-half-up (positive finite)
  return (short)((__float_as_uint(f) + 0x8000u) >> 16);
}
DEV float bf2f(short s) { return __uint_as_float(((unsigned)(unsigned short)s) << 16); }

DEV void gld_lds16(const short* g, short* l) {
  __builtin_amdgcn_global_load_lds(
      (const __attribute__((address_space(1))) void*)g,
      (__attribute__((address_space(3))) void*)l, 16, 0, 0);
}

// LDS transpose read (4x16 bf16 subtile, lane gets column lane&15)
DEV u32x2 trr(unsigned lds_byte) {
  u32x2 r;
  asm volatile("ds_read_b64_tr_b16 %0, %1" : "=&v"(r) : "v"(lds_byte));
  return r;
}

// XCD-bijective swizzle (m204)
DEV int xcd_swz(int id, int nwg) {
  int q8 = nwg >> 3, r8 = nwg & 7, xcd = id & 7, off = id >> 3;
  return (xcd < r8) ? (xcd * (q8 + 1) + off) : (r8 * (q8 + 1) + (xcd - r8) * q8 + off);
}

// ================= 64xBN tile bf16 BT GEMM, dbuf + chunk-swizzle =================
// BN=128: waves 1x4. BN=64: waves 2x2.
// flags: 1=+bias[col], 2=exact GELU, 4=accumulate into fp32 C, 8=bf16 out
template<int BN>
__global__ __launch_bounds__(256) void gemm_t(
    const short* __restrict__ A, const short* __restrict__ B, void* __restrict__ Cv,
    const float* __restrict__ bias,
    int M, int N, int K, int lda, int ldb, int ldc, int flags)
{
  constexpr int BPASS = BN / 32;
  constexpr int MI = (BN == 128) ? 4 : 2;
  __shared__ __align__(16) short As[2][64 * 64];
  __shared__ __align__(16) short Bs[2][BN * 64];
  int nwg = gridDim.x * gridDim.y;
  int idl = blockIdx.y * gridDim.x + blockIdx.x;
  int swz = xcd_swz(idl, nwg);
  int bx = swz % gridDim.x, by = swz / gridDim.x;
  int m0 = by * 64, n0 = bx * BN;
  int tid = threadIdx.x, lane = tid & 63, w = tid >> 6;
  int lr = lane & 15, kg = lane >> 4;
  int wrb = (BN == 128) ? 0 : (w >> 1) * 32;
  int wcb = (BN == 128) ? w * 32 : (w & 1) * 32;
  f4v acc[MI][2] = {};
  int NT = K >> 6;

#define STAGE(bufi, k0)                                                   \
  {                                                                       \
    _Pragma("unroll")                                                     \
    for (int p = 0; p < 2; ++p) {                                         \
      int ch = p * 256 + w * 64 + lane;                                   \
      int row = ch >> 3, c = (ch & 7) ^ (row & 7);                        \
      gld_lds16(A + (long)(m0 + row) * lda + (k0) + c * 8,                \
                &As[bufi][(p * 256 + w * 64) * 8]);                       \
    }                                                                     \
    _Pragma("unroll")                                                     \
    for (int p = 0; p < BPASS; ++p) {                                     \
      int ch = p * 256 + w * 64 + lane;                                   \
      int row = ch >> 3, c = (ch & 7) ^ (row & 7);                        \
      gld_lds16(B + (long)(n0 + row) * ldb + (k0) + c * 8,                \
                &Bs[bufi][(p * 256 + w * 64) * 8]);                       \
    }                                                                     \
  }

  STAGE(0, 0)
  for (int t = 0; t < NT; ++t) {
    int buf = t & 1;
    if (t + 1 < NT) {
      STAGE(buf ^ 1, (t + 1) * 64)
      if constexpr (BN == 128)
        asm volatile("s_waitcnt vmcnt(6)" ::: "memory");
      else
        asm volatile("s_waitcnt vmcnt(4)" ::: "memory");
    } else {
      asm volatile("s_waitcnt vmcnt(0)" ::: "memory");
    }
    __builtin_amdgcn_s_barrier();
    #pragma unroll
    for (int ks = 0; ks < 2; ++ks) {
      s8v av[MI], bv[2];
      #pragma unroll
      for (int mi = 0; mi < MI; ++mi) {
        int row = wrb + mi * 16 + lr;
        int sl = (ks * 4 + kg) ^ (row & 7);
        av[mi] = *(const s8v*)&As[buf][row * 64 + sl * 8];
      }
      #pragma unroll
      for (int ni = 0; ni < 2; ++ni) {
        int row = wcb + ni * 16 + lr;
        int sl = (ks * 4 + kg) ^ (row & 7);
        bv[ni] = *(const s8v*)&Bs[buf][row * 64 + sl * 8];
      }
      #pragma unroll
      for (int mi = 0; mi < MI; ++mi)
        #pragma unroll
        for (int ni = 0; ni < 2; ++ni)
          acc[mi][ni] = __builtin_amdgcn_mfma_f32_16x16x32_bf16(av[mi], bv[ni], acc[mi][ni], 0, 0, 0);
    }
    asm volatile("s_waitcnt lgkmcnt(0)" ::: "memory");
    __builtin_amdgcn_s_barrier();
  }
#undef STAGE

  float* Cf = (float*)Cv;
  short* Cb = (short*)Cv;
  #pragma unroll
  for (int mi = 0; mi < MI; ++mi)
    #pragma unroll
    for (int ni = 0; ni < 2; ++ni) {
      int col = n0 + wcb + ni * 16 + lr;
      float bvv = (flags & 1) ? bias[col] : 0.f;
      #pragma unroll
      for (int j = 0; j < 4; ++j) {
        int row = m0 + wrb + mi * 16 + kg * 4 + j;
        if (row >= M) continue;
        float v = acc[mi][ni][j] + bvv;
        if (flags & 2) v = 0.5f * v * (1.f + erff(v * 0.70710678118f));
        long ci = (long)row * ldc + col;
        if (flags & 8) Cb[ci] = f2bf(v);
        else { if (flags & 4) v += Cf[ci]; Cf[ci] = v; }
      }
    }
}

// ---------------- fused flash attention: in-block 2-way KV split ----------------
// grid 544 = 32 z * 17 qtiles; block 512 = 2 groups * 4 waves.
__global__ __launch_bounds__(512) void flash_k(
    const short* __restrict__ qkv, short* __restrict__ O)
{
  int swz = xcd_swz(blockIdx.x, 544);
  int z = swz / 17, qt = swz - z * 17;
  int zb = z >> 3, zh = z & 7;
  const short* base = qkv + (long)zb * 1025 * 1536 + zh * 192;
  const short* Qg = base;
  const short* Kg = base + 64;
  const short* Vg = base + 128;
  int q0 = qt * 64;
  int tid = threadIdx.x, lane = tid & 63, w = tid >> 6;
  int g = w >> 2, wl = w & 3;
  int lr = lane & 15, kg = lane >> 4;
  int kt0 = g * 8;

  __shared__ __align__(16) short Ks[2][2][64 * 64];
  __shared__ __align__(16) short Vs[2][2][64 * 64];

  s8v aq[2];
  {
    long qrow = q0 + wl * 16 + lr;
    aq[0] = *(const s8v*)(Qg + qrow * 1536 + kg * 8);
    aq[1] = *(const s8v*)(Qg + qrow * 1536 + 32 + kg * 8);
  }

  unsigned vsbase = (unsigned)(unsigned long long)
      (__attribute__((address_space(3))) void*)&Vs[0][0][0];
  unsigned vtr = (unsigned)(lr * 8 + kg * 1024);

#define STAGE_K(bufi, kv0)                                                 \
  {                                                                        \
    int s0 = wl * 128;                                                     \
    _Pragma("unroll")                                                      \
    for (int i = 0; i < 2; ++i) {                                          \
      int s = s0 + i * 64 + lane;                                          \
      int row = s >> 3, c = (s & 7) ^ (row & 7);                           \
      gld_lds16(Kg + (long)((kv0) + row) * 1536 + c * 8,                   \
                &Ks[g][bufi][(s0 + i * 64) * 8]);                          \
    }                                                                      \
  }
#define STAGE_V(bufi, kv0)                                                 \
  {                                                                        \
    int s0 = wl * 128;                                                     \
    _Pragma("unroll")                                                      \
    for (int i = 0; i < 2; ++i) {                                          \
      int ch = s0 + i * 64 + lane;                                         \
      int st = ch >> 3, r = (ch & 7) >> 1, hh = ch & 1;                    \
      int key = (kv0) + (st >> 2) * 4 + r;                                 \
      int d = (st & 3) * 16 + hh * 8;                                      \
      gld_lds16(Vg + (long)key * 1536 + d,                                 \
                &Vs[g][bufi][(s0 + i * 64) * 8]);                          \
    }                                                                      \
  }

  f4v acc[4] = {};
  float m_run = -3.0e38f, l_run = 0.f;
  const float C2 = 0.18033688011112042f;
  const float THR = 44.36f;

  STAGE_K(0, kt0 * 64)
  STAGE_V(0, kt0 * 64)
  asm volatile("s_waitcnt vmcnt(0)" ::: "memory");
  __builtin_amdgcn_s_barrier();

  for (int kt = kt0; kt < kt0 + 8; ++kt) {
    int cur = (kt - kt0) & 1;
    if (kt + 1 < kt0 + 8) {
      STAGE_K(cur ^ 1, (kt + 1) * 64)
      STAGE_V(cur ^ 1, (kt + 1) * 64)
    }

    f4v sa[4] = {};
    __builtin_amdgcn_s_setprio(1);
    #pragma unroll
    for (int ni = 0; ni < 4; ++ni) {
      int row = ni * 16 + lr;
      #pragma unroll
      for (int ks = 0; ks < 2; ++ks) {
        int c = (ks * 4 + kg) ^ (row & 7);
        s8v kf = *(const s8v*)&Ks[g][cur][row * 64 + c * 8];
        sa[ni] = __builtin_amdgcn_mfma_f32_16x16x32_bf16(kf, aq[ks], sa[ni], 0, 0, 0);
      }
    }
    __builtin_amdgcn_s_setprio(0);

    float tm = -3.0e38f;
    #pragma unroll
    for (int ni = 0; ni < 4; ++ni)
      #pragma unroll
      for (int jj = 0; jj < 4; ++jj) tm = fmaxf(tm, sa[ni][jj]);
    tm = fmaxf(tm, __shfl_xor(tm, 16));
    tm = fmaxf(tm, __shfl_xor(tm, 32));
    bool need = !__all(tm <= m_run + THR);
    float scale = 1.f;
    if (need) {
      float m_new = fmaxf(m_run, tm);
      scale = exp2f((m_run - m_new) * C2);
      m_run = m_new;
    }
    float mC = m_run * C2;
    float pv[4][4];
    float ts = 0.f;
    #pragma unroll
    for (int ni = 0; ni < 4; ++ni)
      #pragma unroll
      for (int jj = 0; jj < 4; ++jj) {
        float p = exp2f(fmaf(sa[ni][jj], C2, -mC));
        pv[ni][jj] = p;
        ts += p;
      }
    ts += __shfl_xor(ts, 16);
    ts += __shfl_xor(ts, 32);
    l_run = l_run * scale + ts;
    if (need) {
      float scq[4];
      #pragma unroll
      for (int jj = 0; jj < 4; ++jj)
        scq[jj] = __shfl(scale, kg * 4 + jj + 16 * kg);
      #pragma unroll
      for (int ni = 0; ni < 4; ++ni)
        #pragma unroll
        for (int jj = 0; jj < 4; ++jj) acc[ni][jj] *= scq[jj];
    }

    unsigned pr[4][2];
    #pragma unroll
    for (int ni = 0; ni < 4; ++ni)
      #pragma unroll
      for (int hh = 0; hh < 2; ++hh) {
        unsigned lo = (unsigned)(unsigned short)f2bf_fast(pv[ni][2 * hh]);
        unsigned hi = (unsigned)(unsigned short)f2bf_fast(pv[ni][2 * hh + 1]);
        pr[ni][hh] = lo | (hi << 16);
      }
    union PU { s8v v; unsigned u[4]; };
    PU apu[2];
    #pragma unroll
    for (int ks = 0; ks < 2; ++ks)
      #pragma unroll
      for (int t = 0; t < 4; ++t) {
        unsigned src = (kg & 2) ? pr[2 * ks + 1][t & 1] : pr[2 * ks][t & 1];
        apu[ks].u[t] = __shfl(src, lr + 16 * (2 * (kg & 1) + (t >> 1)));
      }

    u32x2 tr[4][2][2];
    unsigned vb = vsbase + (unsigned)(g * 2 + cur) * 8192u + vtr;
    #pragma unroll
    for (int ni = 0; ni < 4; ++ni)
      #pragma unroll
      for (int ks = 0; ks < 2; ++ks) {
        tr[ni][ks][0] = trr(vb + ni * 128 + ks * 4096);
        tr[ni][ks][1] = trr(vb + ni * 128 + ks * 4096 + 512);
      }
    asm volatile("s_waitcnt lgkmcnt(0)" ::: "memory");
    __builtin_amdgcn_sched_barrier(0);

    __builtin_amdgcn_s_setprio(1);
    #pragma unroll
    for (int ni = 0; ni < 4; ++ni) {
      #pragma unroll
      for (int ks = 0; ks < 2; ++ks) {
        union { s8v v; u32x2 u2[2]; } bb;
        bb.u2[0] = tr[ni][ks][0];
        bb.u2[1] = tr[ni][ks][1];
        acc[ni] = __builtin_amdgcn_mfma_f32_16x16x32_bf16(apu[ks].v, bb.v, acc[ni], 0, 0, 0);
      }
    }
    __builtin_amdgcn_s_setprio(0);
    asm volatile("s_waitcnt lgkmcnt(0)" ::: "memory");
    asm volatile("s_waitcnt vmcnt(0)" ::: "memory");
    __builtin_amdgcn_s_barrier();
  }
#undef STAGE_K
#undef STAGE_V

  if (g) {
    s8v k0 = *(const s8v*)(Kg + 1024L * 1536 + kg * 8);
    s8v k1 = *(const s8v*)(Kg + 1024L * 1536 + 32 + kg * 8);
    float s = 0.f;
    #pragma unroll
    for (int j = 0; j < 8; ++j)
      s += bf2f(aq[0][j]) * bf2f(k0[j]) + bf2f(aq[1][j]) * bf2f(k1[j]);
    s += __shfl_xor(s, 16);
    s += __shfl_xor(s, 32);
    float m_new = fmaxf(m_run, s);
    float sc = exp2f((m_run - m_new) * C2);
    float p = exp2f((s - m_new) * C2);
    m_run = m_new;
    l_run = l_run * sc + p;
    float vrow[4];
    #pragma unroll
    for (int ni = 0; ni < 4; ++ni)
      vrow[ni] = bf2f(Vg[1024L * 1536 + ni * 16 + lr]);
    float scq[4], pq[4];
    #pragma unroll
    for (int jj = 0; jj < 4; ++jj) {
      scq[jj] = __shfl(sc, kg * 4 + jj + 16 * kg);
      pq[jj]  = __shfl(p,  kg * 4 + jj + 16 * kg);
    }
    #pragma unroll
    for (int ni = 0; ni < 4; ++ni)
      #pragma unroll
      for (int jj = 0; jj < 4; ++jj)
        acc[ni][jj] = acc[ni][jj] * scq[jj] + pq[jj] * vrow[ni];
  }

  // in-block combine (LDS reuse)
  float* AccL = (float*)&Ks[0][0][0];
  float* MLs  = (float*)&Vs[0][0][0];
  if (kg == 0) {
    MLs[(g * 64 + wl * 16 + lr) * 2]     = m_run;
    MLs[(g * 64 + wl * 16 + lr) * 2 + 1] = l_run;
  }
  if (g == 0) {
    #pragma unroll
    for (int ni = 0; ni < 4; ++ni)
      #pragma unroll
      for (int jj = 0; jj < 4; ++jj)
        AccL[(wl * 16 + kg * 4 + jj) * 64 + ni * 16 + lr] = acc[ni][jj];
  }
  asm volatile("s_waitcnt lgkmcnt(0)" ::: "memory");
  __builtin_amdgcn_s_barrier();
  if (g == 1) {
    float m0 = MLs[(wl * 16 + lr) * 2], l0 = MLs[(wl * 16 + lr) * 2 + 1];
    float M = fmaxf(m0, m_run);
    float w0 = exp2f((m0 - M) * C2), w1 = exp2f((m_run - M) * C2);
    float inv = 1.f / (l0 * w0 + l_run * w1);
    float c0 = w0 * inv, c1 = w1 * inv;
    float c0q[4], c1q[4];
    #pragma unroll
    for (int jj = 0; jj < 4; ++jj) {
      c0q[jj] = __shfl(c0, kg * 4 + jj + 16 * kg);
      c1q[jj] = __shfl(c1, kg * 4 + jj + 16 * kg);
    }
    #pragma unroll
    for (int ni = 0; ni < 4; ++ni)
      #pragma unroll
      for (int jj = 0; jj < 4; ++jj) {
        int row = q0 + wl * 16 + kg * 4 + jj;
        if (row < 1025) {
          float a0 = AccL[(wl * 16 + kg * 4 + jj) * 64 + ni * 16 + lr];
          O[((long)(zb * 1025 + row)) * 512 + zh * 64 + ni * 16 + lr] =
              f2bf(a0 * c0q[jj] + acc[ni][jj] * c1q[jj]);
        }
      }
  }
}

// ---------------- weight transpose+convert ----------------
DEV void tconv_body(const float* w, short* wt, int K, int N, int bx, int by, int tid)
{
  __shared__ float tile[32][33];
  int n0 = bx * 32, k0 = by * 32;
  int tx = tid & 31, ty = tid >> 5;
  #pragma unroll
  for (int j = 0; j < 4; ++j)
    tile[ty + j * 8][tx] = w[(long)(k0 + ty + j * 8) * N + n0 + tx];
  __syncthreads();
  #pragma unroll
  for (int j = 0; j < 4; ++j)
    wt[(long)(n0 + ty + j * 8) * K + k0 + tx] = f2bf(tile[tx][ty + j * 8]);
}

DEV void tconv_dispatch(int r, int tid,
    const float* sq, const float* sm, const float* sf1, const float* sf2,
    short* dq, short* dm, short* df1, short* df2)
{
  if (r < 1152)       tconv_body(sq,  dq,  768, 1536, r % 48,          r / 48,          tid);
  else if (r < 1536)  tconv_body(sm,  dm,  512, 768,  (r - 1152) % 24, (r - 1152) / 24, tid);
  else if (r < 3072)  tconv_body(sf1, df1, 768, 2048, (r - 1536) % 64, (r - 1536) / 64, tid);
  else                tconv_body(sf2, df2, 2048, 768, (r - 3072) % 24, (r - 3072) / 24, tid);
}

// per-layer variant (fallback path)
__global__ __launch_bounds__(256) void tconv4_k(
    const float* __restrict__ sq, const float* __restrict__ sm,
    const float* __restrict__ sf1, const float* __restrict__ sf2,
    short* __restrict__ dq, short* __restrict__ dm,
    short* __restrict__ df1, short* __restrict__ df2)
{
  tconv_dispatch(blockIdx.x, threadIdx.x, sq, sm, sf1, sf2, dq, dm, df1, df2);
}

// all-layers variant: grid 12*4608; layer l's buffers at wAll + l*4718592
__global__ __launch_bounds__(256) void tconvall_k(
    const float* __restrict__ qkv_w, const float* __restrict__ merge_w,
    const float* __restrict__ f1w, const float* __restrict__ f2w,
    short* __restrict__ wAll)
{
  int id = blockIdx.x;
  int l = id / 4608, r = id - l * 4608;
  short* base = wAll + (long)l * 4718592;
  tconv_dispatch(r, threadIdx.x,
      qkv_w + (long)l * 768 * 1536, merge_w + (long)l * 512 * 768,
      f1w + (long)l * 768 * 2048, f2w + (long)l * 2048 * 768,
      base, base + 1179648, base + 1572864, base + 3145728);
}

// ---------------- prep: conv_w fp32->bf16 (zone 0) + im2col (zone 1) ----------------
__global__ __launch_bounds__(256) void prep_k(const float* __restrict__ conv_w,
    short* __restrict__ wcv, const float* __restrict__ x, short* __restrict__ A)
{
  if (blockIdx.x < 768) {
    int i = blockIdx.x * 256 + threadIdx.x;
    wcv[i] = f2bf(conv_w[i]);
  } else {
    int i = (blockIdx.x - 768) * 256 + threadIdx.x;
    int k = i & 255, row = i >> 8;
    int px = k & 15, py = k >> 4;
    int gx = row & 31, gy = (row >> 5) & 31, b = row >> 10;
    A[i] = f2bf(x[((long)(b * 512) + gy * 16 + py) * 512 + gx * 16 + px]);
  }
}

// ---------------- LayerNorm D=768: one wave per row, float4, no LDS ----------------
DEV void st4(float* p, f4v v) { *(f4v*)p = v; }
DEV void st4(short* p, f4v v) {
  s4v o = { f2bf(v[0]), f2bf(v[1]), f2bf(v[2]), f2bf(v[3]) };
  *(s4v*)p = o;
}

template<typename OT>
__global__ __launch_bounds__(256) void ln_k(const float* __restrict__ x,
    const float* __restrict__ g, const float* __restrict__ b,
    OT* __restrict__ y, int rows)
{
  int row = blockIdx.x * 4 + (threadIdx.x >> 6);
  if (row >= rows) return;
  int lane = threadIdx.x & 63;
  const float* xr = x + (long)row * 768;
  f4v v[3];
  #pragma unroll
  for (int i = 0; i < 3; ++i) v[i] = *(const f4v*)(xr + i * 256 + lane * 4);
  float s = 0.f, s2 = 0.f;
  #pragma unroll
  for (int i = 0; i < 3; ++i)
    #pragma unroll
    for (int j = 0; j < 4; ++j) { s += v[i][j]; s2 += v[i][j] * v[i][j]; }
  #pragma unroll
  for (int o = 1; o < 64; o <<= 1) { s += __shfl_xor(s, o); s2 += __shfl_xor(s2, o); }
  float mean = s * (1.f / 768.f);
  float var = s2 * (1.f / 768.f) - mean * mean;
  float r = rsqrtf(var + 1e-5f);
  OT* yr = y + (long)row * 768;
  #pragma unroll
  for (int i = 0; i < 3; ++i) {
    f4v gg = *(const f4v*)(g + i * 256 + lane * 4);
    f4v bb = *(const f4v*)(b + i * 256 + lane * 4);
    f4v o;
    #pragma unroll
    for (int j = 0; j < 4; ++j) o[j] = (v[i][j] - mean) * r * gg[j] + bb[j];
    st4(yr + i * 256 + lane * 4, o);
  }
}

// ---------------- t = concat(cls, tok) + pos ----------------
__global__ __launch_bounds__(256) void assemble_k(const short* __restrict__ tok,
    const float* __restrict__ cls, const float* __restrict__ pos, float* __restrict__ t)
{
  int i = blockIdx.x * 256 + threadIdx.x;
  int d = i % 768; int rn = i / 768; int n = rn % 1025; int b = rn / 1025;
  float v = (n == 0) ? cls[d] : bf2f(tok[((long)(b * 1024 + n - 1)) * 768 + d]);
  t[i] = v + pos[n * 768 + d];
}

extern "C" void kernel_launch(void* const* d_in, const int* in_sizes, int n_in,
                              void* d_out, int out_size, void* d_ws, size_t ws_size,
                              hipStream_t stream)
{
  const float* x       = (const float*)d_in[0];
  const float* conv_w  = (const float*)d_in[1];
  const float* conv_b  = (const float*)d_in[2];
  const float* cls     = (const float*)d_in[3];
  const float* pos     = (const float*)d_in[4];
  const float* qkv_w   = (const float*)d_in[5];
  const float* merge_w = (const float*)d_in[6];
  const float* merge_b = (const float*)d_in[7];
  const float* ln1_s   = (const float*)d_in[8];
  const float* ln1_b   = (const float*)d_in[9];
  const float* ln2_s   = (const float*)d_in[10];
  const float* ln2_b   = (const float*)d_in[11];
  const float* ffn_w1  = (const float*)d_in[12];
  const float* ffn_b1  = (const float*)d_in[13];
  const float* ffn_w2  = (const float*)d_in[14];
  const float* ffn_b2  = (const float*)d_in[15];
  const float* lnf_s   = (const float*)d_in[16];
  const float* lnf_b   = (const float*)d_in[17];

  char* wsp = (char*)d_ws;
  size_t o = 0;
  auto take = [&](size_t bytes) { char* r = wsp + o; o = (o + bytes + 255) & ~(size_t)255; return r; };
  short* wq   = (short*)take(1536ul * 768 * 2);
  short* wm   = (short*)take(768ul * 512 * 2);
  short* wf1  = (short*)take(2048ul * 768 * 2);
  short* wf2  = (short*)take(768ul * 2048 * 2);
  short* wcv  = (short*)take(768ul * 256 * 2);
  float* t    = (float*)take(4100ul * 768 * 4);
  char*  hO   = take(4352ul * 768 * 2);              // h bf16 OR O bf16 (rows padded)
  short* qkv  = (short*)take(4ul * 1025 * 1536 * 2);
  char*  fV   = take(4352ul * 2048 * 2);             // f (padded) OR (im2col + tok)
  take(2ul << 20);                                   // slack for tile over-reads

  // optional all-layers weight cache (runtime ws_size check; deterministic)
  const size_t WALL_BYTES = 12ul * 4718592 * 2;
  bool useAll = (o + WALL_BYTES + (2ul << 20)) <= ws_size;
  short* wAll = nullptr;
  if (useAll) wAll = (short*)take(WALL_BYTES);

  short* h   = (short*)hO;
  short* O   = (short*)hO;
  short* f   = (short*)fV;
  short* imc = (short*)fV;
  short* tok = (short*)(fV + 4096ul * 256 * 2);

  dim3 blk(256), blk512(512);

  // ---- patch embed ----
  prep_k<<<768 + 4096, blk, 0, stream>>>(conv_w, wcv, x, imc);
  gemm_t<64><<<dim3(12, 64), blk, 0, stream>>>(imc, wcv, tok, conv_b,
      4096, 768, 256, 256, 256, 768, 1 | 8);
  assemble_k<<<12300, blk, 0, stream>>>(tok, cls, pos, t);
  if (useAll)
    tconvall_k<<<12 * 4608, blk, 0, stream>>>(qkv_w, merge_w, ffn_w1, ffn_w2, wAll);

  for (int i = 0; i < 12; ++i) {
    const short *wq_i, *wm_i, *wf1_i, *wf2_i;
    if (useAll) {
      short* base = wAll + (long)i * 4718592;
      wq_i = base; wm_i = base + 1179648; wf1_i = base + 1572864; wf2_i = base + 3145728;
    } else {
      tconv4_k<<<4608, blk, 0, stream>>>(
          qkv_w + (long)i * 768 * 1536, merge_w + (long)i * 512 * 768,
          ffn_w1 + (long)i * 768 * 2048, ffn_w2 + (long)i * 2048 * 768,
          wq, wm, wf1, wf2);
      wq_i = wq; wm_i = wm; wf1_i = wf1; wf2_i = wf2;
    }

    // h = LN1(t)
    ln_k<short><<<1025, blk, 0, stream>>>(t, ln1_s + i * 768, ln1_b + i * 768, h, 4100);
    // qkv = h @ qkv_w
    gemm_t<64><<<dim3(24, 65), blk, 0, stream>>>(h, wq_i, qkv, nullptr,
        4100, 1536, 768, 768, 768, 1536, 8);
    // fused attention (in-block KV split) -> O
    flash_k<<<544, blk512, 0, stream>>>(qkv, O);
    // t += O @ merge_w + merge_b
    gemm_t<64><<<dim3(12, 65), blk, 0, stream>>>(O, wm_i, t, merge_b + i * 768,
        4100, 768, 512, 512, 512, 768, 1 | 4);
    // h = LN2(t)
    ln_k<short><<<1025, blk, 0, stream>>>(t, ln2_s + i * 768, ln2_b + i * 768, h, 4100);
    // f = GELU(h @ ffn_w1 + b1)
    gemm_t<64><<<dim3(32, 65), blk, 0, stream>>>(h, wf1_i, f, ffn_b1 + i * 2048,
        4100, 2048, 768, 768, 768, 2048, 1 | 2 | 8);
    // t += f @ ffn_w2 + b2
    gemm_t<64><<<dim3(12, 65), blk, 0, stream>>>(f, wf2_i, t, ffn_b2 + i * 768,
        4100, 768, 2048, 2048, 2048, 768, 1 | 4);
  }
  ln_k<float><<<1025, blk, 0, stream>>>(t, lnf_s, lnf_b, (float*)d_out, 4100);
}

// Round 17
// 1966.357 us; speedup vs baseline: 1.0618x; 1.0154x over previous
//
#include <hip/hip_runtime.h>

#define DEV __device__ __forceinline__

typedef short s4v __attribute__((ext_vector_type(4)));
typedef short s8v __attribute__((ext_vector_type(8)));
typedef float f4v __attribute__((ext_vector_type(4)));
typedef unsigned int u32x2 __attribute__((ext_vector_type(2)));

DEV short f2bf(float f) {
  unsigned u = __float_as_uint(f);
  u += 0x7FFFu + ((u >> 16) & 1u);
  return (short)(u >> 16);
}
DEV short f2bf_fast(float f) {           // round-half-up (positive finite)
  return (short)((__float_as_uint(f) + 0x8000u) >> 16);
}
DEV float bf2f(short s) { return __uint_as_float(((unsigned)(unsigned short)s) << 16); }

DEV void gld_lds16(const short* g, short* l) {
  __builtin_amdgcn_global_load_lds(
      (const __attribute__((address_space(1))) void*)g,
      (__attribute__((address_space(3))) void*)l, 16, 0, 0);
}

// LDS transpose read (4x16 bf16 subtile, lane gets column lane&15)
DEV u32x2 trr(unsigned lds_byte) {
  u32x2 r;
  asm volatile("ds_read_b64_tr_b16 %0, %1" : "=&v"(r) : "v"(lds_byte));
  return r;
}

// XCD-bijective swizzle (m204)
DEV int xcd_swz(int id, int nwg) {
  int q8 = nwg >> 3, r8 = nwg & 7, xcd = id & 7, off = id >> 3;
  return (xcd < r8) ? (xcd * (q8 + 1) + off) : (r8 * (q8 + 1) + (xcd - r8) * q8 + off);
}

// ================= 64xBN tile bf16 BT GEMM, dbuf + chunk-swizzle =================
// BN=128: waves 1x4. BN=64: waves 2x2.
// flags: 1=+bias[col], 2=exact GELU, 4=accumulate into fp32 C, 8=bf16 out
template<int BN>
__global__ __launch_bounds__(256) void gemm_t(
    const short* __restrict__ A, const short* __restrict__ B, void* __restrict__ Cv,
    const float* __restrict__ bias,
    int M, int N, int K, int lda, int ldb, int ldc, int flags)
{
  constexpr int BPASS = BN / 32;
  constexpr int MI = (BN == 128) ? 4 : 2;
  __shared__ __align__(16) short As[2][64 * 64];
  __shared__ __align__(16) short Bs[2][BN * 64];
  int nwg = gridDim.x * gridDim.y;
  int idl = blockIdx.y * gridDim.x + blockIdx.x;
  int swz = xcd_swz(idl, nwg);
  int bx = swz % gridDim.x, by = swz / gridDim.x;
  int m0 = by * 64, n0 = bx * BN;
  int tid = threadIdx.x, lane = tid & 63, w = tid >> 6;
  int lr = lane & 15, kg = lane >> 4;
  int wrb = (BN == 128) ? 0 : (w >> 1) * 32;
  int wcb = (BN == 128) ? w * 32 : (w & 1) * 32;
  f4v acc[MI][2] = {};
  int NT = K >> 6;

#define STAGE(bufi, k0)                                                   \
  {                                                                       \
    _Pragma("unroll")                                                     \
    for (int p = 0; p < 2; ++p) {                                         \
      int ch = p * 256 + w * 64 + lane;                                   \
      int row = ch >> 3, c = (ch & 7) ^ (row & 7);                        \
      gld_lds16(A + (long)(m0 + row) * lda + (k0) + c * 8,                \
                &As[bufi][(p * 256 + w * 64) * 8]);                       \
    }                                                                     \
    _Pragma("unroll")                                                     \
    for (int p = 0; p < BPASS; ++p) {                                     \
      int ch = p * 256 + w * 64 + lane;                                   \
      int row = ch >> 3, c = (ch & 7) ^ (row & 7);                        \
      gld_lds16(B + (long)(n0 + row) * ldb + (k0) + c * 8,                \
                &Bs[bufi][(p * 256 + w * 64) * 8]);                       \
    }                                                                     \
  }

  STAGE(0, 0)
  for (int t = 0; t < NT; ++t) {
    int buf = t & 1;
    if (t + 1 < NT) {
      STAGE(buf ^ 1, (t + 1) * 64)
      if constexpr (BN == 128)
        asm volatile("s_waitcnt vmcnt(6)" ::: "memory");
      else
        asm volatile("s_waitcnt vmcnt(4)" ::: "memory");
    } else {
      asm volatile("s_waitcnt vmcnt(0)" ::: "memory");
    }
    __builtin_amdgcn_s_barrier();
    #pragma unroll
    for (int ks = 0; ks < 2; ++ks) {
      s8v av[MI], bv[2];
      #pragma unroll
      for (int mi = 0; mi < MI; ++mi) {
        int row = wrb + mi * 16 + lr;
        int sl = (ks * 4 + kg) ^ (row & 7);
        av[mi] = *(const s8v*)&As[buf][row * 64 + sl * 8];
      }
      #pragma unroll
      for (int ni = 0; ni < 2; ++ni) {
        int row = wcb + ni * 16 + lr;
        int sl = (ks * 4 + kg) ^ (row & 7);
        bv[ni] = *(const s8v*)&Bs[buf][row * 64 + sl * 8];
      }
      #pragma unroll
      for (int mi = 0; mi < MI; ++mi)
        #pragma unroll
        for (int ni = 0; ni < 2; ++ni)
          acc[mi][ni] = __builtin_amdgcn_mfma_f32_16x16x32_bf16(av[mi], bv[ni], acc[mi][ni], 0, 0, 0);
    }
    asm volatile("s_waitcnt lgkmcnt(0)" ::: "memory");
    __builtin_amdgcn_s_barrier();
  }
#undef STAGE

  float* Cf = (float*)Cv;
  short* Cb = (short*)Cv;
  #pragma unroll
  for (int mi = 0; mi < MI; ++mi)
    #pragma unroll
    for (int ni = 0; ni < 2; ++ni) {
      int col = n0 + wcb + ni * 16 + lr;
      float bvv = (flags & 1) ? bias[col] : 0.f;
      #pragma unroll
      for (int j = 0; j < 4; ++j) {
        int row = m0 + wrb + mi * 16 + kg * 4 + j;
        if (row >= M) continue;
        float v = acc[mi][ni][j] + bvv;
        if (flags & 2) v = 0.5f * v * (1.f + erff(v * 0.70710678118f));
        long ci = (long)row * ldc + col;
        if (flags & 8) Cb[ci] = f2bf(v);
        else { if (flags & 4) v += Cf[ci]; Cf[ci] = v; }
      }
    }
}

// ---------------- fused flash attention: in-block 2-way KV split ----------------
// grid 544 = 32 z * 17 qtiles; block 512 = 2 groups * 4 waves.
__global__ __launch_bounds__(512) void flash_k(
    const short* __restrict__ qkv, short* __restrict__ O)
{
  int swz = xcd_swz(blockIdx.x, 544);
  int z = swz / 17, qt = swz - z * 17;
  int zb = z >> 3, zh = z & 7;
  const short* base = qkv + (long)zb * 1025 * 1536 + zh * 192;
  const short* Qg = base;
  const short* Kg = base + 64;
  const short* Vg = base + 128;
  int q0 = qt * 64;
  int tid = threadIdx.x, lane = tid & 63, w = tid >> 6;
  int g = w >> 2, wl = w & 3;
  int lr = lane & 15, kg = lane >> 4;
  int kt0 = g * 8;

  __shared__ __align__(16) short Ks[2][2][64 * 64];
  __shared__ __align__(16) short Vs[2][2][64 * 64];

  s8v aq[2];
  {
    long qrow = q0 + wl * 16 + lr;
    aq[0] = *(const s8v*)(Qg + qrow * 1536 + kg * 8);
    aq[1] = *(const s8v*)(Qg + qrow * 1536 + 32 + kg * 8);
  }

  unsigned vsbase = (unsigned)(unsigned long long)
      (__attribute__((address_space(3))) void*)&Vs[0][0][0];
  unsigned vtr = (unsigned)(lr * 8 + kg * 1024);

#define STAGE_K(bufi, kv0)                                                 \
  {                                                                        \
    int s0 = wl * 128;                                                     \
    _Pragma("unroll")                                                      \
    for (int i = 0; i < 2; ++i) {                                          \
      int s = s0 + i * 64 + lane;                                          \
      int row = s >> 3, c = (s & 7) ^ (row & 7);                           \
      gld_lds16(Kg + (long)((kv0) + row) * 1536 + c * 8,                   \
                &Ks[g][bufi][(s0 + i * 64) * 8]);                          \
    }                                                                      \
  }
#define STAGE_V(bufi, kv0)                                                 \
  {                                                                        \
    int s0 = wl * 128;                                                     \
    _Pragma("unroll")                                                      \
    for (int i = 0; i < 2; ++i) {                                          \
      int ch = s0 + i * 64 + lane;                                         \
      int st = ch >> 3, r = (ch & 7) >> 1, hh = ch & 1;                    \
      int key = (kv0) + (st >> 2) * 4 + r;                                 \
      int d = (st & 3) * 16 + hh * 8;                                      \
      gld_lds16(Vg + (long)key * 1536 + d,                                 \
                &Vs[g][bufi][(s0 + i * 64) * 8]);                          \
    }                                                                      \
  }

  f4v acc[4] = {};
  float m_run = -3.0e38f, l_run = 0.f;
  const float C2 = 0.18033688011112042f;
  const float THR = 44.36f;

  STAGE_K(0, kt0 * 64)
  STAGE_V(0, kt0 * 64)
  asm volatile("s_waitcnt vmcnt(0)" ::: "memory");
  __builtin_amdgcn_s_barrier();

  for (int kt = kt0; kt < kt0 + 8; ++kt) {
    int cur = (kt - kt0) & 1;
    if (kt + 1 < kt0 + 8) {
      STAGE_K(cur ^ 1, (kt + 1) * 64)
      STAGE_V(cur ^ 1, (kt + 1) * 64)
    }

    f4v sa[4] = {};
    __builtin_amdgcn_s_setprio(1);
    #pragma unroll
    for (int ni = 0; ni < 4; ++ni) {
      int row = ni * 16 + lr;
      #pragma unroll
      for (int ks = 0; ks < 2; ++ks) {
        int c = (ks * 4 + kg) ^ (row & 7);
        s8v kf = *(const s8v*)&Ks[g][cur][row * 64 + c * 8];
        sa[ni] = __builtin_amdgcn_mfma_f32_16x16x32_bf16(kf, aq[ks], sa[ni], 0, 0, 0);
      }
    }
    __builtin_amdgcn_s_setprio(0);

    float tm = -3.0e38f;
    #pragma unroll
    for (int ni = 0; ni < 4; ++ni)
      #pragma unroll
      for (int jj = 0; jj < 4; ++jj) tm = fmaxf(tm, sa[ni][jj]);
    tm = fmaxf(tm, __shfl_xor(tm, 16));
    tm = fmaxf(tm, __shfl_xor(tm, 32));
    bool need = !__all(tm <= m_run + THR);
    float scale = 1.f;
    if (need) {
      float m_new = fmaxf(m_run, tm);
      scale = exp2f((m_run - m_new) * C2);
      m_run = m_new;
    }
    float mC = m_run * C2;
    float pv[4][4];
    float ts = 0.f;
    #pragma unroll
    for (int ni = 0; ni < 4; ++ni)
      #pragma unroll
      for (int jj = 0; jj < 4; ++jj) {
        float p = exp2f(fmaf(sa[ni][jj], C2, -mC));
        pv[ni][jj] = p;
        ts += p;
      }
    ts += __shfl_xor(ts, 16);
    ts += __shfl_xor(ts, 32);
    l_run = l_run * scale + ts;
    if (need) {
      float scq[4];
      #pragma unroll
      for (int jj = 0; jj < 4; ++jj)
        scq[jj] = __shfl(scale, kg * 4 + jj + 16 * kg);
      #pragma unroll
      for (int ni = 0; ni < 4; ++ni)
        #pragma unroll
        for (int jj = 0; jj < 4; ++jj) acc[ni][jj] *= scq[jj];
    }

    unsigned pr[4][2];
    #pragma unroll
    for (int ni = 0; ni < 4; ++ni)
      #pragma unroll
      for (int hh = 0; hh < 2; ++hh) {
        unsigned lo = (unsigned)(unsigned short)f2bf_fast(pv[ni][2 * hh]);
        unsigned hi = (unsigned)(unsigned short)f2bf_fast(pv[ni][2 * hh + 1]);
        pr[ni][hh] = lo | (hi << 16);
      }
    union PU { s8v v; unsigned u[4]; };
    PU apu[2];
    #pragma unroll
    for (int ks = 0; ks < 2; ++ks)
      #pragma unroll
      for (int t = 0; t < 4; ++t) {
        unsigned src = (kg & 2) ? pr[2 * ks + 1][t & 1] : pr[2 * ks][t & 1];
        apu[ks].u[t] = __shfl(src, lr + 16 * (2 * (kg & 1) + (t >> 1)));
      }

    u32x2 tr[4][2][2];
    unsigned vb = vsbase + (unsigned)(g * 2 + cur) * 8192u + vtr;
    #pragma unroll
    for (int ni = 0; ni < 4; ++ni)
      #pragma unroll
      for (int ks = 0; ks < 2; ++ks) {
        tr[ni][ks][0] = trr(vb + ni * 128 + ks * 4096);
        tr[ni][ks][1] = trr(vb + ni * 128 + ks * 4096 + 512);
      }
    asm volatile("s_waitcnt lgkmcnt(0)" ::: "memory");
    __builtin_amdgcn_sched_barrier(0);

    __builtin_amdgcn_s_setprio(1);
    #pragma unroll
    for (int ni = 0; ni < 4; ++ni) {
      #pragma unroll
      for (int ks = 0; ks < 2; ++ks) {
        union { s8v v; u32x2 u2[2]; } bb;
        bb.u2[0] = tr[ni][ks][0];
        bb.u2[1] = tr[ni][ks][1];
        acc[ni] = __builtin_amdgcn_mfma_f32_16x16x32_bf16(apu[ks].v, bb.v, acc[ni], 0, 0, 0);
      }
    }
    __builtin_amdgcn_s_setprio(0);
    asm volatile("s_waitcnt lgkmcnt(0)" ::: "memory");
    asm volatile("s_waitcnt vmcnt(0)" ::: "memory");
    __builtin_amdgcn_s_barrier();
  }
#undef STAGE_K
#undef STAGE_V

  if (g) {
    s8v k0 = *(const s8v*)(Kg + 1024L * 1536 + kg * 8);
    s8v k1 = *(const s8v*)(Kg + 1024L * 1536 + 32 + kg * 8);
    float s = 0.f;
    #pragma unroll
    for (int j = 0; j < 8; ++j)
      s += bf2f(aq[0][j]) * bf2f(k0[j]) + bf2f(aq[1][j]) * bf2f(k1[j]);
    s += __shfl_xor(s, 16);
    s += __shfl_xor(s, 32);
    float m_new = fmaxf(m_run, s);
    float sc = exp2f((m_run - m_new) * C2);
    float p = exp2f((s - m_new) * C2);
    m_run = m_new;
    l_run = l_run * sc + p;
    float vrow[4];
    #pragma unroll
    for (int ni = 0; ni < 4; ++ni)
      vrow[ni] = bf2f(Vg[1024L * 1536 + ni * 16 + lr]);
    float scq[4], pq[4];
    #pragma unroll
    for (int jj = 0; jj < 4; ++jj) {
      scq[jj] = __shfl(sc, kg * 4 + jj + 16 * kg);
      pq[jj]  = __shfl(p,  kg * 4 + jj + 16 * kg);
    }
    #pragma unroll
    for (int ni = 0; ni < 4; ++ni)
      #pragma unroll
      for (int jj = 0; jj < 4; ++jj)
        acc[ni][jj] = acc[ni][jj] * scq[jj] + pq[jj] * vrow[ni];
  }

  // in-block combine (LDS reuse)
  float* AccL = (float*)&Ks[0][0][0];
  float* MLs  = (float*)&Vs[0][0][0];
  if (kg == 0) {
    MLs[(g * 64 + wl * 16 + lr) * 2]     = m_run;
    MLs[(g * 64 + wl * 16 + lr) * 2 + 1] = l_run;
  }
  if (g == 0) {
    #pragma unroll
    for (int ni = 0; ni < 4; ++ni)
      #pragma unroll
      for (int jj = 0; jj < 4; ++jj)
        AccL[(wl * 16 + kg * 4 + jj) * 64 + ni * 16 + lr] = acc[ni][jj];
  }
  asm volatile("s_waitcnt lgkmcnt(0)" ::: "memory");
  __builtin_amdgcn_s_barrier();
  if (g == 1) {
    float m0 = MLs[(wl * 16 + lr) * 2], l0 = MLs[(wl * 16 + lr) * 2 + 1];
    float M = fmaxf(m0, m_run);
    float w0 = exp2f((m0 - M) * C2), w1 = exp2f((m_run - M) * C2);
    float inv = 1.f / (l0 * w0 + l_run * w1);
    float c0 = w0 * inv, c1 = w1 * inv;
    float c0q[4], c1q[4];
    #pragma unroll
    for (int jj = 0; jj < 4; ++jj) {
      c0q[jj] = __shfl(c0, kg * 4 + jj + 16 * kg);
      c1q[jj] = __shfl(c1, kg * 4 + jj + 16 * kg);
    }
    #pragma unroll
    for (int ni = 0; ni < 4; ++ni)
      #pragma unroll
      for (int jj = 0; jj < 4; ++jj) {
        int row = q0 + wl * 16 + kg * 4 + jj;
        if (row < 1025) {
          float a0 = AccL[(wl * 16 + kg * 4 + jj) * 64 + ni * 16 + lr];
          O[((long)(zb * 1025 + row)) * 512 + zh * 64 + ni * 16 + lr] =
              f2bf(a0 * c0q[jj] + acc[ni][jj] * c1q[jj]);
        }
      }
  }
}

// ---------------- per-layer weight transpose+convert (short2 writes) ----------------
// tile[k_local][n_local] = w[k0+k_local][n0+n_local]; write wt[n][k] = tile[k][n].
DEV void tconv_body(const float* w, short* wt, int K, int N, int bx, int by, int tid)
{
  __shared__ float tile[32][34];
  int n0 = bx * 32, k0 = by * 32;
  int tx = tid & 31, ty = tid >> 5;
  #pragma unroll
  for (int j = 0; j < 4; ++j)
    tile[ty + j * 8][tx] = w[(long)(k0 + ty + j * 8) * N + n0 + tx];
  __syncthreads();
  // write phase: kp = k-pair (0..15), rr+j*16 = n row; short2 along K
  int kp = tid & 15, rr = tid >> 4;
  #pragma unroll
  for (int j = 0; j < 2; ++j) {
    int n = rr + j * 16;
    short lo = f2bf(tile[kp * 2][n]);
    short hi = f2bf(tile[kp * 2 + 1][n]);
    *(short2*)&wt[(long)(n0 + n) * K + k0 + kp * 2] = make_short2(lo, hi);
  }
}

__global__ __launch_bounds__(256) void tconv4_k(
    const float* __restrict__ sq, const float* __restrict__ sm,
    const float* __restrict__ sf1, const float* __restrict__ sf2,
    short* __restrict__ dq, short* __restrict__ dm,
    short* __restrict__ df1, short* __restrict__ df2)
{
  int r = blockIdx.x, tid = threadIdx.x;
  if (r < 1152)       tconv_body(sq,  dq,  768, 1536, r % 48,          r / 48,          tid);
  else if (r < 1536)  tconv_body(sm,  dm,  512, 768,  (r - 1152) % 24, (r - 1152) / 24, tid);
  else if (r < 3072)  tconv_body(sf1, df1, 768, 2048, (r - 1536) % 64, (r - 1536) / 64, tid);
  else                tconv_body(sf2, df2, 2048, 768, (r - 3072) % 24, (r - 3072) / 24, tid);
}

// ---------------- prep: conv_w fp32->bf16 (zone 0) + im2col (zone 1) ----------------
__global__ __launch_bounds__(256) void prep_k(const float* __restrict__ conv_w,
    short* __restrict__ wcv, const float* __restrict__ x, short* __restrict__ A)
{
  if (blockIdx.x < 768) {
    int i = blockIdx.x * 256 + threadIdx.x;
    wcv[i] = f2bf(conv_w[i]);
  } else {
    int i = (blockIdx.x - 768) * 256 + threadIdx.x;
    int k = i & 255, row = i >> 8;
    int px = k & 15, py = k >> 4;
    int gx = row & 31, gy = (row >> 5) & 31, b = row >> 10;
    A[i] = f2bf(x[((long)(b * 512) + gy * 16 + py) * 512 + gx * 16 + px]);
  }
}

// ---------------- LayerNorm D=768: one wave per row, float4, no LDS ----------------
DEV void st4(float* p, f4v v) { *(f4v*)p = v; }
DEV void st4(short* p, f4v v) {
  s4v o = { f2bf(v[0]), f2bf(v[1]), f2bf(v[2]), f2bf(v[3]) };
  *(s4v*)p = o;
}

template<typename OT>
__global__ __launch_bounds__(256) void ln_k(const float* __restrict__ x,
    const float* __restrict__ g, const float* __restrict__ b,
    OT* __restrict__ y, int rows)
{
  int row = blockIdx.x * 4 + (threadIdx.x >> 6);
  if (row >= rows) return;
  int lane = threadIdx.x & 63;
  const float* xr = x + (long)row * 768;
  f4v v[3];
  #pragma unroll
  for (int i = 0; i < 3; ++i) v[i] = *(const f4v*)(xr + i * 256 + lane * 4);
  float s = 0.f, s2 = 0.f;
  #pragma unroll
  for (int i = 0; i < 3; ++i)
    #pragma unroll
    for (int j = 0; j < 4; ++j) { s += v[i][j]; s2 += v[i][j] * v[i][j]; }
  #pragma unroll
  for (int o = 1; o < 64; o <<= 1) { s += __shfl_xor(s, o); s2 += __shfl_xor(s2, o); }
  float mean = s * (1.f / 768.f);
  float var = s2 * (1.f / 768.f) - mean * mean;
  float r = rsqrtf(var + 1e-5f);
  OT* yr = y + (long)row * 768;
  #pragma unroll
  for (int i = 0; i < 3; ++i) {
    f4v gg = *(const f4v*)(g + i * 256 + lane * 4);
    f4v bb = *(const f4v*)(b + i * 256 + lane * 4);
    f4v o;
    #pragma unroll
    for (int j = 0; j < 4; ++j) o[j] = (v[i][j] - mean) * r * gg[j] + bb[j];
    st4(yr + i * 256 + lane * 4, o);
  }
}

// ---------------- t = concat(cls, tok) + pos ----------------
__global__ __launch_bounds__(256) void assemble_k(const short* __restrict__ tok,
    const float* __restrict__ cls, const float* __restrict__ pos, float* __restrict__ t)
{
  int i = blockIdx.x * 256 + threadIdx.x;
  int d = i % 768; int rn = i / 768; int n = rn % 1025; int b = rn / 1025;
  float v = (n == 0) ? cls[d] : bf2f(tok[((long)(b * 1024 + n - 1)) * 768 + d]);
  t[i] = v + pos[n * 768 + d];
}

extern "C" void kernel_launch(void* const* d_in, const int* in_sizes, int n_in,
                              void* d_out, int out_size, void* d_ws, size_t ws_size,
                              hipStream_t stream)
{
  const float* x       = (const float*)d_in[0];
  const float* conv_w  = (const float*)d_in[1];
  const float* conv_b  = (const float*)d_in[2];
  const float* cls     = (const float*)d_in[3];
  const float* pos     = (const float*)d_in[4];
  const float* qkv_w   = (const float*)d_in[5];
  const float* merge_w = (const float*)d_in[6];
  const float* merge_b = (const float*)d_in[7];
  const float* ln1_s   = (const float*)d_in[8];
  const float* ln1_b   = (const float*)d_in[9];
  const float* ln2_s   = (const float*)d_in[10];
  const float* ln2_b   = (const float*)d_in[11];
  const float* ffn_w1  = (const float*)d_in[12];
  const float* ffn_b1  = (const float*)d_in[13];
  const float* ffn_w2  = (const float*)d_in[14];
  const float* ffn_b2  = (const float*)d_in[15];
  const float* lnf_s   = (const float*)d_in[16];
  const float* lnf_b   = (const float*)d_in[17];

  char* wsp = (char*)d_ws;
  size_t o = 0;
  auto take = [&](size_t bytes) { char* r = wsp + o; o = (o + bytes + 255) & ~(size_t)255; return r; };
  short* wq   = (short*)take(1536ul * 768 * 2);
  short* wm   = (short*)take(768ul * 512 * 2);
  short* wf1  = (short*)take(2048ul * 768 * 2);
  short* wf2  = (short*)take(768ul * 2048 * 2);
  short* wcv  = (short*)take(768ul * 256 * 2);
  float* t    = (float*)take(4100ul * 768 * 4);
  char*  hO   = take(4352ul * 768 * 2);              // h bf16 OR O bf16 (rows padded)
  short* qkv  = (short*)take(4ul * 1025 * 1536 * 2);
  char*  fV   = take(4352ul * 2048 * 2);             // f (padded) OR (im2col + tok)
  take(2ul << 20);                                   // slack for tile over-reads

  short* h   = (short*)hO;
  short* O   = (short*)hO;
  short* f   = (short*)fV;
  short* imc = (short*)fV;
  short* tok = (short*)(fV + 4096ul * 256 * 2);

  dim3 blk(256), blk512(512);

  // ---- patch embed ----
  prep_k<<<768 + 4096, blk, 0, stream>>>(conv_w, wcv, x, imc);
  gemm_t<64><<<dim3(12, 64), blk, 0, stream>>>(imc, wcv, tok, conv_b,
      4096, 768, 256, 256, 256, 768, 1 | 8);
  assemble_k<<<12300, blk, 0, stream>>>(tok, cls, pos, t);

  for (int i = 0; i < 12; ++i) {
    tconv4_k<<<4608, blk, 0, stream>>>(
        qkv_w + (long)i * 768 * 1536, merge_w + (long)i * 512 * 768,
        ffn_w1 + (long)i * 768 * 2048, ffn_w2 + (long)i * 2048 * 768,
        wq, wm, wf1, wf2);

    // h = LN1(t)
    ln_k<short><<<1025, blk, 0, stream>>>(t, ln1_s + i * 768, ln1_b + i * 768, h, 4100);
    // qkv = h @ qkv_w
    gemm_t<64><<<dim3(24, 65), blk, 0, stream>>>(h, wq, qkv, nullptr,
        4100, 1536, 768, 768, 768, 1536, 8);
    // fused attention (in-block KV split) -> O
    flash_k<<<544, blk512, 0, stream>>>(qkv, O);
    // t += O @ merge_w + merge_b
    gemm_t<64><<<dim3(12, 65), blk, 0, stream>>>(O, wm, t, merge_b + i * 768,
        4100, 768, 512, 512, 512, 768, 1 | 4);
    // h = LN2(t)
    ln_k<short><<<1025, blk, 0, stream>>>(t, ln2_s + i * 768, ln2_b + i * 768, h, 4100);
    // f = GELU(h @ ffn_w1 + b1)
    gemm_t<64><<<dim3(32, 65), blk, 0, stream>>>(h, wf1, f, ffn_b1 + i * 2048,
        4100, 2048, 768, 768, 768, 2048, 1 | 2 | 8);
    // t += f @ ffn_w2 + b2
    gemm_t<64><<<dim3(12, 65), blk, 0, stream>>>(f, wf2, t, ffn_b2 + i * 768,
        4100, 768, 2048, 2048, 2048, 768, 1 | 4);
  }
  ln_k<float><<<1025, blk, 0, stream>>>(t, lnf_s, lnf_b, (float*)d_out, 4100);
}